// Round 6
// baseline (87.105 us; speedup 1.0000x reference)
//
#include <hip/hip_runtime.h>
#include <hip/hip_bf16.h>

#define NVIS   16384
#define NTAC   2048
#define NPRED  (NVIS + NTAC)     // 18432
#define NMODEL 8192

#define BLK    256
#define PPT    3                 // pred points per thread
#define TILE   (BLK * PPT)       // 768 pred points per block
#define NTILE  (NPRED / TILE)    // 24
#define CHUNK  256               // model points per block
#define NCHUNK (NMODEL / CHUNK)  // 32
// hot grid = 24 x 32 = 768 blocks = 3 blocks/CU

#define BIGF     3.4e38f
#define INF_BITS 0x7F800000u

// Math: |(p-t)R/s - m|^2 = |p - m''|^2 / s^2,  m'' = t + s * m * R^T.
// So only model points get transformed. dist_raw = |p|^2 + 2*(0.5|m''|^2 - p.m'')
// and the 1/s^2 plus the means are applied in the final reduce.

// ws layout: model4[NMODEL] (x,y,z, 0.5|m''|^2) | pmin[NPRED] (uint bits)

// Kernel T: transform model points (blocks 0..31), init pmin=+inf (blocks 32..103).
__global__ __launch_bounds__(BLK) void cd_setup_kernel(
    const float* __restrict__ model,
    const float* __restrict__ scale,
    const float* __restrict__ state,
    float4* __restrict__ model4,
    unsigned* __restrict__ pmin)
{
    const int tid = threadIdx.x;
    const int bid = blockIdx.x;

    if (bid < NMODEL / BLK) {
        const float ax = state[3], ay = state[4], az = state[5];
        const float sx = sinf(ax), cx = cosf(ax);
        const float sy = sinf(ay), cy = cosf(ay);
        const float sz = sinf(az), cz = cosf(az);
        const float R00 = cz * cy;
        const float R01 = cz * sy * sx - sz * cx;
        const float R02 = cz * sy * cx + sz * sx;
        const float R10 = sz * cy;
        const float R11 = sz * sy * sx + cz * cx;
        const float R12 = sz * sy * cx - cz * sx;
        const float R20 = -sy;
        const float R21 = cy * sx;
        const float R22 = cy * cx;
        const float t0 = state[0], t1 = state[1], t2 = state[2];
        const float s  = scale[0];

        const int mid = bid * BLK + tid;
        const float* mp = model + 3 * mid;
        const float mx = mp[0], my = mp[1], mz = mp[2];
        // m'' = t + s * (m . R^T):  x-comp dots with R's row 0, etc.
        const float wx = fmaf(s, mx * R00 + my * R01 + mz * R02, t0);
        const float wy = fmaf(s, mx * R10 + my * R11 + mz * R12, t1);
        const float wz = fmaf(s, mx * R20 + my * R21 + mz * R22, t2);
        model4[mid] = make_float4(wx, wy, wz, 0.5f * (wx * wx + wy * wy + wz * wz));
    } else {
        const int pid = (bid - NMODEL / BLK) * BLK + tid;
        pmin[pid] = INF_BITS;
    }
}

// Kernel P: hot loop. Raw pred points, wave-uniform model reads (s_load path),
// no LDS, no syncthreads; per-point result via atomicMin on positive-float bits.
__global__ __launch_bounds__(BLK) void cd_partial_kernel(
    const float* __restrict__ vis,
    const float* __restrict__ tac,
    const float4* __restrict__ model4,
    unsigned* __restrict__ pmin)
{
    const int tid   = threadIdx.x;
    const int tile  = blockIdx.x;
    const int chunk = blockIdx.y;

    float nx[PPT], ny[PPT], nz[PPT], pa[PPT];
    #pragma unroll
    for (int k = 0; k < PPT; ++k) {
        const int pid = tile * TILE + k * BLK + tid;
        const float* pp = (pid < NVIS) ? (vis + 3 * pid) : (tac + 3 * (pid - NVIS));
        const float p0 = pp[0], p1 = pp[1], p2 = pp[2];
        pa[k] = p0 * p0 + p1 * p1 + p2 * p2;
        nx[k] = -p0; ny[k] = -p1; nz[k] = -p2;   // negate once: inner is pure fma
    }

    const float4* __restrict__ mrow = model4 + chunk * CHUNK;  // uniform base

    float b0 = BIGF, b1 = BIGF, b2 = BIGF;
    #pragma unroll 8
    for (int j = 0; j < CHUNK; ++j) {
        const float4 m = mrow[j];   // uniform address -> scalar load (SGPR operands)
        b0 = fminf(b0, fmaf(nx[0], m.x, fmaf(ny[0], m.y, fmaf(nz[0], m.z, m.w))));
        b1 = fminf(b1, fmaf(nx[1], m.x, fmaf(ny[1], m.y, fmaf(nz[1], m.z, m.w))));
        b2 = fminf(b2, fmaf(nx[2], m.x, fmaf(ny[2], m.y, fmaf(nz[2], m.z, m.w))));
    }

    const int pbase = tile * TILE + tid;
    atomicMin(&pmin[pbase + 0 * BLK], __float_as_uint(fmaf(2.0f, b0, pa[0])));
    atomicMin(&pmin[pbase + 1 * BLK], __float_as_uint(fmaf(2.0f, b1, pa[1])));
    atomicMin(&pmin[pbase + 2 * BLK], __float_as_uint(fmaf(2.0f, b2, pa[2])));
}

// Kernel R: weighted sum of per-point mins; scale applied here.
__global__ __launch_bounds__(BLK) void cd_reduce_kernel(
    const unsigned* __restrict__ pmin,
    const float* __restrict__ scale,
    float* __restrict__ out)
{
    const int tid = threadIdx.x;
    const int pid = blockIdx.x * BLK + tid;

    float v = __uint_as_float(pmin[pid]);
    #pragma unroll
    for (int off = 32; off > 0; off >>= 1)
        v += __shfl_down(v, off, 64);

    __shared__ float sh[BLK / 64];
    if ((tid & 63) == 0) sh[tid >> 6] = v;
    __syncthreads();

    if (tid == 0) {
        const float s = scale[0];
        const float inv2 = 1.0f / (s * s);
        const float t = sh[0] + sh[1] + sh[2] + sh[3];
        const float scaled = (blockIdx.x < NVIS / BLK) ? t * inv2 * (1.0f / (float)NVIS)
                                                       : t * inv2 * (0.1f / (float)NTAC);
        atomicAdd(out, scaled);
    }
}

extern "C" void kernel_launch(void* const* d_in, const int* in_sizes, int n_in,
                              void* d_out, int out_size, void* d_ws, size_t ws_size,
                              hipStream_t stream) {
    const float* vis   = (const float*)d_in[0];
    const float* tac   = (const float*)d_in[1];
    const float* model = (const float*)d_in[2];
    const float* scale = (const float*)d_in[3];
    const float* state = (const float*)d_in[4];
    float* out = (float*)d_out;

    float4*   model4 = (float4*)d_ws;             // 128 KB
    unsigned* pmin   = (unsigned*)(model4 + NMODEL); // 72 KB

    hipMemsetAsync(out, 0, sizeof(float), stream);

    cd_setup_kernel<<<NMODEL / BLK + NPRED / BLK, BLK, 0, stream>>>(
        model, scale, state, model4, pmin);

    dim3 grid(NTILE, NCHUNK);            // (24, 32) = 768 blocks
    cd_partial_kernel<<<grid, BLK, 0, stream>>>(vis, tac, model4, pmin);

    cd_reduce_kernel<<<NPRED / BLK, BLK, 0, stream>>>(pmin, scale, out);
}

// Round 7
// 78.467 us; speedup vs baseline: 1.1101x; 1.1101x over previous
//
#include <hip/hip_runtime.h>
#include <hip/hip_bf16.h>

#define NVIS   16384
#define NTAC   2048
#define NPRED  (NVIS + NTAC)     // 18432
#define NMODEL 8192

#define BLK    256
#define PPT    3                 // pred points per thread
#define TILE   (BLK * PPT)       // 768 pred points per block
#define NTILE  (NPRED / TILE)    // 24
#define CHUNK  256               // model points per block
#define NCHUNK (NMODEL / CHUNK)  // 32
// hot grid = 24 x 32 = 768 blocks = 3 blocks/CU

#define BIGF   3.4e38f

// Math: |(p-t)R/s - m|^2 = |p - m''|^2 / s^2,  m'' = t + s * m * R^T.
// P stores raw-space |p - m''|^2 via atomicMin on positive-float bits;
// R applies 1/s^2 and the weighted means.
// ws layout: pmin[NPRED] (uint bits; memset to 0xFF = +inf for positive floats)

// Kernel P: fused model-transform + chunk scan + atomicMin. 3 blocks/CU.
__global__ __launch_bounds__(BLK) void cd_partial_kernel(
    const float* __restrict__ vis,
    const float* __restrict__ tac,
    const float* __restrict__ model,
    const float* __restrict__ scale,
    const float* __restrict__ state,
    unsigned* __restrict__ pmin)
{
    __shared__ float4 sm[CHUNK];

    const int tid   = threadIdx.x;
    const int tile  = blockIdx.x;
    const int chunk = blockIdx.y;

    // --- per-block: rotation + transform own model chunk (1 pt/thread) ---
    {
        const float ax = state[3], ay = state[4], az = state[5];
        const float sx = sinf(ax), cx = cosf(ax);
        const float sy = sinf(ay), cy = cosf(ay);
        const float sz = sinf(az), cz = cosf(az);
        const float R00 = cz * cy;
        const float R01 = cz * sy * sx - sz * cx;
        const float R02 = cz * sy * cx + sz * sx;
        const float R10 = sz * cy;
        const float R11 = sz * sy * sx + cz * cx;
        const float R12 = sz * sy * cx - cz * sx;
        const float R20 = -sy;
        const float R21 = cy * sx;
        const float R22 = cy * cx;
        const float t0 = state[0], t1 = state[1], t2 = state[2];
        const float s  = scale[0];

        const float* mp = model + 3 * (chunk * CHUNK + tid);
        const float mx = mp[0], my = mp[1], mz = mp[2];
        // m'' = t + s * (m . R^T)
        const float wx = fmaf(s, mx * R00 + my * R01 + mz * R02, t0);
        const float wy = fmaf(s, mx * R10 + my * R11 + mz * R12, t1);
        const float wz = fmaf(s, mx * R20 + my * R21 + mz * R22, t2);
        sm[tid] = make_float4(wx, wy, wz, 0.5f * (wx * wx + wy * wy + wz * wz));
    }

    // --- load raw pred points (coalesced-ish, 3 dwords each) ---
    float nx[PPT], ny[PPT], nz[PPT], pa[PPT];
    #pragma unroll
    for (int k = 0; k < PPT; ++k) {
        const int pid = tile * TILE + k * BLK + tid;
        const float* pp = (pid < NVIS) ? (vis + 3 * pid) : (tac + 3 * (pid - NVIS));
        const float p0 = pp[0], p1 = pp[1], p2 = pp[2];
        pa[k] = p0 * p0 + p1 * p1 + p2 * p2;
        nx[k] = -p0; ny[k] = -p1; nz[k] = -p2;   // negate once: inner is pure fma
    }

    __syncthreads();

    float b0 = BIGF, b1 = BIGF, b2 = BIGF;
    #pragma unroll 8
    for (int j = 0; j < CHUNK; ++j) {
        const float4 m = sm[j];    // wave-uniform -> LDS broadcast
        b0 = fminf(b0, fmaf(nx[0], m.x, fmaf(ny[0], m.y, fmaf(nz[0], m.z, m.w))));
        b1 = fminf(b1, fmaf(nx[1], m.x, fmaf(ny[1], m.y, fmaf(nz[1], m.z, m.w))));
        b2 = fminf(b2, fmaf(nx[2], m.x, fmaf(ny[2], m.y, fmaf(nz[2], m.z, m.w))));
    }

    const int pbase = tile * TILE + tid;
    atomicMin(&pmin[pbase + 0 * BLK], __float_as_uint(fmaf(2.0f, b0, pa[0])));
    atomicMin(&pmin[pbase + 1 * BLK], __float_as_uint(fmaf(2.0f, b1, pa[1])));
    atomicMin(&pmin[pbase + 2 * BLK], __float_as_uint(fmaf(2.0f, b2, pa[2])));
}

// Kernel R: single block, 1024 threads. 72 KB from L2, writes out[0] directly.
__global__ __launch_bounds__(1024) void cd_reduce_kernel(
    const unsigned* __restrict__ pmin,
    const float* __restrict__ scale,
    float* __restrict__ out)
{
    const int tid = threadIdx.x;

    float vs = 0.0f, ts = 0.0f;
    #pragma unroll
    for (int it = 0; it < NPRED / 1024; ++it) {      // 18 iterations
        const int pid = it * 1024 + tid;
        const float v = __uint_as_float(pmin[pid]);
        if (pid < NVIS) vs += v; else ts += v;
    }

    // wave reduce
    #pragma unroll
    for (int off = 32; off > 0; off >>= 1) {
        vs += __shfl_down(vs, off, 64);
        ts += __shfl_down(ts, off, 64);
    }

    __shared__ float svis[16], stac[16];
    if ((tid & 63) == 0) { svis[tid >> 6] = vs; stac[tid >> 6] = ts; }
    __syncthreads();

    if (tid == 0) {
        float v = 0.0f, t = 0.0f;
        #pragma unroll
        for (int w = 0; w < 16; ++w) { v += svis[w]; t += stac[w]; }
        const float s = scale[0];
        const float inv2 = 1.0f / (s * s);
        out[0] = inv2 * (v * (1.0f / (float)NVIS) + t * (0.1f / (float)NTAC));
    }
}

extern "C" void kernel_launch(void* const* d_in, const int* in_sizes, int n_in,
                              void* d_out, int out_size, void* d_ws, size_t ws_size,
                              hipStream_t stream) {
    const float* vis   = (const float*)d_in[0];
    const float* tac   = (const float*)d_in[1];
    const float* model = (const float*)d_in[2];
    const float* scale = (const float*)d_in[3];
    const float* state = (const float*)d_in[4];
    float* out = (float*)d_out;

    unsigned* pmin = (unsigned*)d_ws;    // NPRED uints = 72 KB

    // 0xFFFFFFFF = uint-max = +inf sentinel for positive-float-bit atomicMin
    hipMemsetAsync(pmin, 0xFF, NPRED * sizeof(unsigned), stream);

    dim3 grid(NTILE, NCHUNK);            // (24, 32) = 768 blocks
    cd_partial_kernel<<<grid, BLK, 0, stream>>>(vis, tac, model, scale, state, pmin);

    cd_reduce_kernel<<<1, 1024, 0, stream>>>(pmin, scale, out);
}

// Round 8
// 76.266 us; speedup vs baseline: 1.1421x; 1.0289x over previous
//
#include <hip/hip_runtime.h>
#include <hip/hip_bf16.h>

#define NVIS   16384
#define NTAC   2048
#define NPRED  (NVIS + NTAC)     // 18432
#define NMODEL 8192

#define BLK    256
#define PPT    3                 // pred points per thread
#define TILE   (BLK * PPT)       // 768 pred points per block
#define NTILE  (NPRED / TILE)    // 24
#define CHUNK  128               // model points per block
#define NCHUNK (NMODEL / CHUNK)  // 64
// hot grid = 24 x 64 = 1536 blocks = 6 blocks/CU = 6 waves/SIMD

#define BIGF   3.4e38f

// Math: |(p-t)R/s - m|^2 = |p - m''|^2 / s^2,  m'' = t + s * m * R^T.
// P stores raw-space |p - m''|^2 via atomicMin on positive-float bits;
// R applies 1/s^2 and the weighted means.
// ws layout: pmin[NPRED] (uint bits; memset to 0xFF = +inf for positive floats)

// Kernel P: fused model-transform + chunk scan + atomicMin.
__global__ __launch_bounds__(BLK) void cd_partial_kernel(
    const float* __restrict__ vis,
    const float* __restrict__ tac,
    const float* __restrict__ model,
    const float* __restrict__ scale,
    const float* __restrict__ state,
    unsigned* __restrict__ pmin)
{
    __shared__ float4 sm[CHUNK];

    const int tid   = threadIdx.x;
    const int tile  = blockIdx.x;
    const int chunk = blockIdx.y;

    // --- per-block: rotation + transform own model chunk (threads 0..127) ---
    if (tid < CHUNK) {
        const float ax = state[3], ay = state[4], az = state[5];
        const float sx = sinf(ax), cx = cosf(ax);
        const float sy = sinf(ay), cy = cosf(ay);
        const float sz = sinf(az), cz = cosf(az);
        const float R00 = cz * cy;
        const float R01 = cz * sy * sx - sz * cx;
        const float R02 = cz * sy * cx + sz * sx;
        const float R10 = sz * cy;
        const float R11 = sz * sy * sx + cz * cx;
        const float R12 = sz * sy * cx - cz * sx;
        const float R20 = -sy;
        const float R21 = cy * sx;
        const float R22 = cy * cx;
        const float t0 = state[0], t1 = state[1], t2 = state[2];
        const float s  = scale[0];

        const float* mp = model + 3 * (chunk * CHUNK + tid);
        const float mx = mp[0], my = mp[1], mz = mp[2];
        // m'' = t + s * (m . R^T)
        const float wx = fmaf(s, mx * R00 + my * R01 + mz * R02, t0);
        const float wy = fmaf(s, mx * R10 + my * R11 + mz * R12, t1);
        const float wz = fmaf(s, mx * R20 + my * R21 + mz * R22, t2);
        sm[tid] = make_float4(wx, wy, wz, 0.5f * (wx * wx + wy * wy + wz * wz));
    }

    // --- load raw pred points ---
    float nx[PPT], ny[PPT], nz[PPT], pa[PPT];
    #pragma unroll
    for (int k = 0; k < PPT; ++k) {
        const int pid = tile * TILE + k * BLK + tid;
        const float* pp = (pid < NVIS) ? (vis + 3 * pid) : (tac + 3 * (pid - NVIS));
        const float p0 = pp[0], p1 = pp[1], p2 = pp[2];
        pa[k] = p0 * p0 + p1 * p1 + p2 * p2;
        nx[k] = -p0; ny[k] = -p1; nz[k] = -p2;   // negate once: inner is pure fma
    }

    __syncthreads();

    // dual accumulators per point: halves the serial fmin dependence depth
    float bA[PPT], bB[PPT];
    #pragma unroll
    for (int k = 0; k < PPT; ++k) { bA[k] = BIGF; bB[k] = BIGF; }

    #pragma unroll 8
    for (int j = 0; j < CHUNK; j += 2) {
        const float4 mA = sm[j];       // wave-uniform -> LDS broadcast
        const float4 mB = sm[j + 1];
        #pragma unroll
        for (int k = 0; k < PPT; ++k) {
            bA[k] = fminf(bA[k], fmaf(nx[k], mA.x, fmaf(ny[k], mA.y, fmaf(nz[k], mA.z, mA.w))));
            bB[k] = fminf(bB[k], fmaf(nx[k], mB.x, fmaf(ny[k], mB.y, fmaf(nz[k], mB.z, mB.w))));
        }
    }

    const int pbase = tile * TILE + tid;
    #pragma unroll
    for (int k = 0; k < PPT; ++k) {
        const float b = fminf(bA[k], bB[k]);
        atomicMin(&pmin[pbase + k * BLK], __float_as_uint(fmaf(2.0f, b, pa[k])));
    }
}

// Kernel R: single block, 1024 threads. 72 KB from L2, writes out[0] directly.
__global__ __launch_bounds__(1024) void cd_reduce_kernel(
    const unsigned* __restrict__ pmin,
    const float* __restrict__ scale,
    float* __restrict__ out)
{
    const int tid = threadIdx.x;

    float vs = 0.0f, ts = 0.0f;
    #pragma unroll
    for (int it = 0; it < NPRED / 1024; ++it) {      // 18 iterations
        const int pid = it * 1024 + tid;
        const float v = __uint_as_float(pmin[pid]);
        if (pid < NVIS) vs += v; else ts += v;
    }

    #pragma unroll
    for (int off = 32; off > 0; off >>= 1) {
        vs += __shfl_down(vs, off, 64);
        ts += __shfl_down(ts, off, 64);
    }

    __shared__ float svis[16], stac[16];
    if ((tid & 63) == 0) { svis[tid >> 6] = vs; stac[tid >> 6] = ts; }
    __syncthreads();

    if (tid == 0) {
        float v = 0.0f, t = 0.0f;
        #pragma unroll
        for (int w = 0; w < 16; ++w) { v += svis[w]; t += stac[w]; }
        const float s = scale[0];
        const float inv2 = 1.0f / (s * s);
        out[0] = inv2 * (v * (1.0f / (float)NVIS) + t * (0.1f / (float)NTAC));
    }
}

extern "C" void kernel_launch(void* const* d_in, const int* in_sizes, int n_in,
                              void* d_out, int out_size, void* d_ws, size_t ws_size,
                              hipStream_t stream) {
    const float* vis   = (const float*)d_in[0];
    const float* tac   = (const float*)d_in[1];
    const float* model = (const float*)d_in[2];
    const float* scale = (const float*)d_in[3];
    const float* state = (const float*)d_in[4];
    float* out = (float*)d_out;

    unsigned* pmin = (unsigned*)d_ws;    // NPRED uints = 72 KB

    // 0xFFFFFFFF = uint-max = +inf sentinel for positive-float-bit atomicMin
    hipMemsetAsync(pmin, 0xFF, NPRED * sizeof(unsigned), stream);

    dim3 grid(NTILE, NCHUNK);            // (24, 64) = 1536 blocks = 6/CU
    cd_partial_kernel<<<grid, BLK, 0, stream>>>(vis, tac, model, scale, state, pmin);

    cd_reduce_kernel<<<1, 1024, 0, stream>>>(pmin, scale, out);
}